// Round 10
// baseline (352.354 us; speedup 1.0000x reference)
//
#include <hip/hip_runtime.h>

typedef _Float16 f16x8 __attribute__((ext_vector_type(8)));
typedef _Float16 f16x4 __attribute__((ext_vector_type(4)));
typedef float f32x4 __attribute__((ext_vector_type(4)));

#define D_IN 768
#define D_H  256
#define SEQ  2048

// async global->LDS, 16B per lane (dest = wave-uniform base + lane*16).
__device__ __forceinline__ void gld16(const void* g, void* l) {
  __builtin_amdgcn_global_load_lds(
      (const __attribute__((address_space(1))) unsigned int*)g,
      (__attribute__((address_space(3))) unsigned int*)l, 16, 0, 0);
}

// ---------------- KPROBE: pure X-streaming read, memcpy pattern --------------
// 2048 blocks x 256 thr (8 blocks/CU, 32 waves/CU). 48 independent float4 per
// thread; per instruction the chip's active window is 8MB contiguous (m13's
// copy pattern). Measures the achievable pure-READ bandwidth in isolation.
__global__ __launch_bounds__(256) void kprobe(const float* __restrict__ X,
                                              float* __restrict__ sink) {
  const int t = threadIdx.x, bid = blockIdx.x;
  const float4* X4 = (const float4*)X;
  const size_t base = (size_t)bid * 256 + t;   // 524288 float4 per sweep
  float a0 = 0.f, a1 = 0.f, a2 = 0.f, a3 = 0.f;
#pragma unroll
  for (int g = 0; g < 48; g += 4) {
    const float4 v0 = X4[base + (size_t)(g + 0) * 524288];
    const float4 v1 = X4[base + (size_t)(g + 1) * 524288];
    const float4 v2 = X4[base + (size_t)(g + 2) * 524288];
    const float4 v3 = X4[base + (size_t)(g + 3) * 524288];
    a0 += v0.x + v0.y + v0.z + v0.w;
    a1 += v1.x + v1.y + v1.z + v1.w;
    a2 += v2.x + v2.y + v2.z + v2.w;
    a3 += v3.x + v3.y + v3.z + v3.w;
  }
  float s = a0 + a1 + a2 + a3;
#pragma unroll
  for (int off = 1; off < 64; off <<= 1) s += __shfl_xor(s, off, 64);
  if ((t & 63) == 0) sink[bid * 4 + (t >> 6)] = s;   // plain store: deterministic
}

// ---------------- K0: W1 [768][256] f32 -> W1T [256][768] f16 (transposed) ---
__global__ __launch_bounds__(256) void k0_w1t(const float* __restrict__ W1,
                                              _Float16* __restrict__ W1T) {
  __shared__ float tl[64][65];
  const int kb = blockIdx.x, nb = blockIdx.y, t = threadIdx.x;
#pragma unroll
  for (int rep = 0; rep < 16; ++rep) {
    const int row = rep * 4 + (t >> 6), col = t & 63;
    tl[row][col] = W1[(size_t)(kb * 64 + row) * D_H + nb * 64 + col];
  }
  __syncthreads();
#pragma unroll
  for (int rep = 0; rep < 16; ++rep) {
    const int n = rep * 4 + (t >> 6), k = t & 63;
    W1T[(size_t)(nb * 64 + n) * D_IN + kb * 64 + k] = (_Float16)tl[k][n];
  }
}

// ---------------- KF: fused logits + local softmax + local pooling -----------
// (R6 verbatim — best passing config.) 2048 blocks x 256 threads, 51KB LDS ->
// 3 blocks/CU. Double-buffered gld_lds staging, raw s_barrier + counted
// vmcnt(6): next tile's loads stay in flight across both barriers.
__global__ __launch_bounds__(256, 3) void kf_fused(const float* __restrict__ X,
    const _Float16* __restrict__ W1T, const float* __restrict__ b1,
    const float* __restrict__ C, _Float16* __restrict__ Ppart,
    float* __restrict__ stats) {
  __shared__ float    Al[2][64][32];
  __shared__ _Float16 Bl[2][256][32];
  __shared__ float    red2[2][64][4];
  __shared__ float    red[64][4];
  const int t = threadIdx.x;
  const int bid = blockIdx.x;
  const size_t M0 = (size_t)bid * 64;

  const int l = t & 63, w = t >> 6;
  const int ar0 = (w * 2 + 0) * 8 + (l >> 3);
  const int ar1 = (w * 2 + 1) * 8 + (l >> 3);
  const int aj = l & 7;
  const float* As0 = X + (M0 + ar0) * D_IN + ((aj ^ (ar0 & 7)) * 4);
  const float* As1 = X + (M0 + ar1) * D_IN + ((aj ^ (ar1 & 7)) * 4);
  const int ad0 = (w * 2 + 0) * 1024 + l * 16;
  const int ad1 = (w * 2 + 1) * 1024 + l * 16;
  const int bj = l & 3;
  const int bc0 = (w * 4 + 0) * 16 + (l >> 2);
  const int bc1 = (w * 4 + 1) * 16 + (l >> 2);
  const int bc2 = (w * 4 + 2) * 16 + (l >> 2);
  const int bc3 = (w * 4 + 3) * 16 + (l >> 2);
  const _Float16* Bs0 = W1T + (size_t)bc0 * D_IN + ((bj ^ (bc0 & 3)) * 8);
  const _Float16* Bs1 = W1T + (size_t)bc1 * D_IN + ((bj ^ (bc1 & 3)) * 8);
  const _Float16* Bs2 = W1T + (size_t)bc2 * D_IN + ((bj ^ (bc2 & 3)) * 8);
  const _Float16* Bs3 = W1T + (size_t)bc3 * D_IN + ((bj ^ (bc3 & 3)) * 8);
  const int bd0 = (w * 4 + 0) * 1024 + l * 16;
  const int bd1 = (w * 4 + 1) * 1024 + l * 16;
  const int bd2 = (w * 4 + 2) * 1024 + l * 16;
  const int bd3 = (w * 4 + 3) * 1024 + l * 16;

  const int wm = w >> 1, wn = w & 1;
  const int l15 = l & 15, kg = l >> 4;
  const int r0 = wm * 32 + l15, r1 = r0 + 16;
  const int sA0lo = ((2 * kg) ^ (r0 & 7)) * 4, sA0hi = ((2 * kg + 1) ^ (r0 & 7)) * 4;
  const int sA1lo = ((2 * kg) ^ (r1 & 7)) * 4, sA1hi = ((2 * kg + 1) ^ (r1 & 7)) * 4;

  f32x4 acc[2][8];
#pragma unroll
  for (int i = 0; i < 2; ++i)
#pragma unroll
    for (int n = 0; n < 8; ++n) acc[i][n] = f32x4{0.f, 0.f, 0.f, 0.f};

  auto issue6 = [&](int kt, int bsel) {
    const int ko = kt * 32;
    char* ab = (char*)&Al[bsel][0][0];
    char* bb = (char*)&Bl[bsel][0][0];
    gld16(As0 + ko, ab + ad0);
    gld16(As1 + ko, ab + ad1);
    gld16(Bs0 + ko, bb + bd0);
    gld16(Bs1 + ko, bb + bd1);
    gld16(Bs2 + ko, bb + bd2);
    gld16(Bs3 + ko, bb + bd3);
  };

  auto compute = [&](int bsel) {
    const float4 a0lo = *(const float4*)&Al[bsel][r0][sA0lo];
    const float4 a0hi = *(const float4*)&Al[bsel][r0][sA0hi];
    const float4 a1lo = *(const float4*)&Al[bsel][r1][sA1lo];
    const float4 a1hi = *(const float4*)&Al[bsel][r1][sA1hi];
    f16x8 af0, af1;
    af0[0] = (_Float16)a0lo.x; af0[1] = (_Float16)a0lo.y;
    af0[2] = (_Float16)a0lo.z; af0[3] = (_Float16)a0lo.w;
    af0[4] = (_Float16)a0hi.x; af0[5] = (_Float16)a0hi.y;
    af0[6] = (_Float16)a0hi.z; af0[7] = (_Float16)a0hi.w;
    af1[0] = (_Float16)a1lo.x; af1[1] = (_Float16)a1lo.y;
    af1[2] = (_Float16)a1lo.z; af1[3] = (_Float16)a1lo.w;
    af1[4] = (_Float16)a1hi.x; af1[5] = (_Float16)a1hi.y;
    af1[6] = (_Float16)a1hi.z; af1[7] = (_Float16)a1hi.w;
#pragma unroll
    for (int n = 0; n < 8; ++n) {
      const int col = wn * 128 + n * 16 + l15;
      const f16x8 bf = *(const f16x8*)&Bl[bsel][col][(kg ^ (col & 3)) * 8];
      acc[0][n] = __builtin_amdgcn_mfma_f32_16x16x32_f16(af0, bf, acc[0][n], 0, 0, 0);
      acc[1][n] = __builtin_amdgcn_mfma_f32_16x16x32_f16(af1, bf, acc[1][n], 0, 0, 0);
    }
  };

  issue6(0, 0);
  issue6(1, 1);

  for (int kp = 0; kp < 11; ++kp) {
#pragma unroll
    for (int par = 0; par < 2; ++par) {
      const int kt = 2 * kp + par;
      asm volatile("s_waitcnt vmcnt(6)" ::: "memory");
      __builtin_amdgcn_sched_barrier(0);
      __builtin_amdgcn_s_barrier();
      compute(par);
      __builtin_amdgcn_sched_barrier(0);
      __builtin_amdgcn_s_barrier();
      if (kt < 22) issue6(kt + 2, par);
      __builtin_amdgcn_sched_barrier(0);
    }
  }
  asm volatile("s_waitcnt vmcnt(6)" ::: "memory");
  __builtin_amdgcn_sched_barrier(0);
  __builtin_amdgcn_s_barrier();
  compute(0);
  __builtin_amdgcn_sched_barrier(0);
  __builtin_amdgcn_s_barrier();
  asm volatile("s_waitcnt vmcnt(0)" ::: "memory");
  __builtin_amdgcn_sched_barrier(0);
  __builtin_amdgcn_s_barrier();
  compute(1);

  float part[2][4][4];
#pragma unroll
  for (int i = 0; i < 2; ++i)
#pragma unroll
    for (int r = 0; r < 4; ++r)
#pragma unroll
      for (int c = 0; c < 4; ++c) part[i][r][c] = 0.f;

#pragma unroll
  for (int n = 0; n < 8; ++n) {
    const int col = wn * 128 + n * 16 + l15;
    const float4 c4 = *(const float4*)(C + col * 4);
    const float bv = b1[col];
#pragma unroll
    for (int i = 0; i < 2; ++i)
#pragma unroll
      for (int r = 0; r < 4; ++r) {
        float z = acc[i][n][r] + bv;
        z = fminf(fmaxf(z, -15.f), 15.f);
        const float e = __expf(2.f * z);
        const float h = (e - 1.f) / (e + 1.f);   // tanh(z)
        part[i][r][0] += h * c4.x;
        part[i][r][1] += h * c4.y;
        part[i][r][2] += h * c4.z;
        part[i][r][3] += h * c4.w;
      }
  }
#pragma unroll
  for (int off = 1; off < 16; off <<= 1) {
#pragma unroll
    for (int i = 0; i < 2; ++i)
#pragma unroll
      for (int r = 0; r < 4; ++r)
#pragma unroll
        for (int c = 0; c < 4; ++c)
          part[i][r][c] += __shfl_xor(part[i][r][c], off, 64);
  }
  if (l15 == 0) {
#pragma unroll
    for (int i = 0; i < 2; ++i)
#pragma unroll
      for (int r = 0; r < 4; ++r)
#pragma unroll
        for (int c = 0; c < 4; ++c)
          red2[wn][wm * 32 + i * 16 + kg * 4 + r][c] = part[i][r][c];
  }
  __syncthreads();

  {
    const int r = t >> 2, c = t & 3;
    red[r][c] = red2[0][r][c] + red2[1][r][c];
  }
  __syncthreads();
  {
    const int c = t >> 6, r = t & 63;
    const float v = red[r][c];
    float m = v;
#pragma unroll
    for (int off = 1; off < 64; off <<= 1) m = fmaxf(m, __shfl_xor(m, off, 64));
    const float e = __expf(v - m);
    red[r][c] = e;
    float s = e;
#pragma unroll
    for (int off = 1; off < 64; off <<= 1) s += __shfl_xor(s, off, 64);
    if (r == 0) {
      stats[(size_t)bid * 8 + c * 2]     = m;
      stats[(size_t)bid * 8 + c * 2 + 1] = s;
    }
  }
  __syncthreads();

  if (t < 192) {
    float pacc[4][4];
#pragma unroll
    for (int c = 0; c < 4; ++c)
#pragma unroll
      for (int j = 0; j < 4; ++j) pacc[c][j] = 0.f;
    const float* Xp = X + M0 * D_IN + t * 4;
#pragma unroll 8
    for (int r = 0; r < 64; ++r) {
      const float4 x4 = *(const float4*)(Xp + (size_t)r * D_IN);
      const float4 w4 = *(const float4*)&red[r][0];
      const float wc[4] = {w4.x, w4.y, w4.z, w4.w};
      const float xv[4] = {x4.x, x4.y, x4.z, x4.w};
#pragma unroll
      for (int c = 0; c < 4; ++c)
#pragma unroll
        for (int j = 0; j < 4; ++j) pacc[c][j] += wc[c] * xv[j];
    }
#pragma unroll
    for (int c = 0; c < 4; ++c) {
      f16x4 o;
#pragma unroll
      for (int j = 0; j < 4; ++j) o[j] = (_Float16)pacc[c][j];
      *(f16x4*)&Ppart[(size_t)bid * 3072 + c * 768 + t * 4] = o;
    }
  }
}

// ---------------- KC: combine 32 block-partials per batch -> pooled ----------
__global__ __launch_bounds__(256) void kc_combine(const _Float16* __restrict__ Ppart,
    const float* __restrict__ stats, float* __restrict__ pooled) {
  const int b = blockIdx.x, t = threadIdx.x;
  __shared__ float sm[32][8];
  __shared__ float Mc[4], Dc[4], fw[32][4];
  sm[t >> 3][t & 7] = stats[((size_t)b * 32 + (t >> 3)) * 8 + (t & 7)];
  __syncthreads();
  if (t < 4) {
    float m = sm[0][t * 2];
#pragma unroll
    for (int blk = 1; blk < 32; ++blk) m = fmaxf(m, sm[blk][t * 2]);
    Mc[t] = m;
  }
  __syncthreads();
  if (t < 128) {
    const int blk = t >> 2, c = t & 3;
    fw[blk][c] = __expf(sm[blk][c * 2] - Mc[c]);
  }
  __syncthreads();
  if (t < 4) {
    float s = 0.f;
#pragma unroll
    for (int blk = 0; blk < 32; ++blk) s += fw[blk][t] * sm[blk][t * 2 + 1];
    Dc[t] = 1.f / s;
  }
  __syncthreads();
#pragma unroll
  for (int c = 0; c < 4; ++c) {
#pragma unroll
    for (int rep = 0; rep < 3; ++rep) {
      const int d = rep * 256 + t;
      float acc = 0.f;
#pragma unroll 4
      for (int blk = 0; blk < 32; ++blk)
        acc += fw[blk][c] * (float)Ppart[((size_t)(b * 32 + blk)) * 3072 + c * 768 + d];
      pooled[(size_t)b * 3072 + c * 768 + d] = fmaxf(acc * Dc[c], 0.f);
    }
  }
}

// ---------------- K4: partial[kc][b][j] = pooled(k-slice) @ W2(k-slice) ------
__global__ __launch_bounds__(256) void k4_partial(const float* __restrict__ pooled,
                                                  const float* __restrict__ W2,
                                                  float* __restrict__ partial) {
  const int jc = blockIdx.x, kc = blockIdx.y, t = threadIdx.x;
  __shared__ float plds[64 * 192];
  __shared__ float sum2[64][64];
  for (int idx = t; idx < 64 * 192; idx += 256) {
    const int b = idx / 192, k = idx - b * 192;
    plds[idx] = pooled[(size_t)b * 3072 + kc * 192 + k];
  }
  __syncthreads();
  const int j = t & 63, kp = t >> 6;
  float acc[64];
#pragma unroll
  for (int b = 0; b < 64; ++b) acc[b] = 0.f;
  const float* W2p = W2 + (size_t)(kc * 192 + kp * 48) * D_IN + jc * 64 + j;
  const float* pb = plds + kp * 48;
  for (int ki = 0; ki < 48; ki += 4) {
    const float w0 = W2p[(size_t)(ki + 0) * D_IN];
    const float w1 = W2p[(size_t)(ki + 1) * D_IN];
    const float w2 = W2p[(size_t)(ki + 2) * D_IN];
    const float w3 = W2p[(size_t)(ki + 3) * D_IN];
#pragma unroll
    for (int b = 0; b < 64; ++b) {
      const float4 p4 = *(const float4*)(pb + b * 192 + ki);
      acc[b] += p4.x * w0 + p4.y * w1 + p4.z * w2 + p4.w * w3;
    }
  }
#pragma unroll
  for (int p = 0; p < 4; ++p) {
    if (kp == p) {
      if (p == 0) {
#pragma unroll
        for (int b = 0; b < 64; ++b) sum2[b][j] = acc[b];
      } else {
#pragma unroll
        for (int b = 0; b < 64; ++b) sum2[b][j] += acc[b];
      }
    }
    __syncthreads();
  }
  for (int idx = t; idx < 4096; idx += 256) {
    const int b = idx >> 6, jj = idx & 63;
    partial[(size_t)kc * 49152 + (size_t)b * D_IN + jc * 64 + jj] = sum2[b][jj];
  }
}

// ---------------- K5: out = sum(partials) + b2 -------------------------------
__global__ __launch_bounds__(256) void k5_final(const float* __restrict__ partial,
                                                const float* __restrict__ b2,
                                                float* __restrict__ out) {
  const int o = blockIdx.x * 256 + threadIdx.x;
  float v = b2[o % D_IN];
#pragma unroll
  for (int p = 0; p < 16; ++p) v += partial[(size_t)p * 49152 + o];
  out[o] = v;
}

extern "C" void kernel_launch(void* const* d_in, const int* in_sizes, int n_in,
                              void* d_out, int out_size, void* d_ws, size_t ws_size,
                              hipStream_t stream) {
  const float* X  = (const float*)d_in[0];
  const float* W1 = (const float*)d_in[1];
  const float* b1 = (const float*)d_in[2];
  const float* C  = (const float*)d_in[3];
  const float* W2 = (const float*)d_in[4];
  const float* b2 = (const float*)d_in[5];
  float* out = (float*)d_out;
  char* ws = (char*)d_ws;
  _Float16* W1T   = (_Float16*)ws;              //         0 ..   393,216
  float* pooled   = (float*)(ws + 393216);      //   393,216 .. 1,179,648
  float* stats    = (float*)(ws + 1179648);     // 1,179,648 .. 1,245,184
  _Float16* Ppart = (_Float16*)(ws + 1245184);  // 1,245,184 .. 13,828,096
  float* partial  = (float*)(ws + 1245184);     // aliases Ppart (used after KC)
  float* sink     = (float*)(ws + 14155776);    // probe scratch (never read)

  kprobe    <<<2048,        256, 0, stream>>>(X, sink);
  k0_w1t    <<<dim3(12, 4), 256, 0, stream>>>(W1, W1T);
  kf_fused  <<<2048,        256, 0, stream>>>(X, W1T, b1, C, Ppart, stats);
  kc_combine<<<64,          256, 0, stream>>>(Ppart, stats, pooled);
  k4_partial<<<dim3(12,16), 256, 0, stream>>>(pooled, W2, partial);
  k5_final  <<<192,         256, 0, stream>>>(partial, b2, out);
}